// Round 4
// baseline (111.704 us; speedup 1.0000x reference)
//
#include <hip/hip_runtime.h>
#include <hip/hip_bf16.h>
#include <math.h>

typedef __bf16 bf16;
typedef __bf16 bf16x8 __attribute__((ext_vector_type(8)));
typedef __bf16 bf16x2 __attribute__((ext_vector_type(2)));
typedef float f32x4 __attribute__((ext_vector_type(4)));
typedef float f32x16 __attribute__((ext_vector_type(16)));

#define D_MODEL 1024
#define SEQ 1024
#define BATCH 4
#define NHEAD 16
#define MTOT (BATCH*SEQ)   // 4096

// scores computed in exp2-space: fold 1/sqrt(64) * log2(e) into Q projection
#define QSCALE 0.18033688011112042f
#define MASKNEG -1e9f

// ---------------- f32 -> bf16 cast: 4 weight matrices only ----------------
__global__ void cast_w(const float* __restrict__ s0, const float* __restrict__ s1,
                       const float* __restrict__ s2, const float* __restrict__ s3,
                       bf16* d0, bf16* d1, bf16* d2, bf16* d3) {
    int z = blockIdx.y;
    const float* s; bf16* d;
    switch (z) {
        case 0: s = s0; d = d0; break;
        case 1: s = s1; d = d1; break;
        case 2: s = s2; d = d2; break;
        default: s = s3; d = d3; break;
    }
    const int n = D_MODEL * D_MODEL;
    int idx = (blockIdx.x * blockDim.x + threadIdx.x) * 8;
    int stride = gridDim.x * blockDim.x * 8;
    for (int i = idx; i < n; i += stride) {
        const float4* p = (const float4*)(s + i);
        float4 a = p[0], b = p[1];
        bf16x8 o;
        o[0] = (bf16)a.x; o[1] = (bf16)a.y; o[2] = (bf16)a.z; o[3] = (bf16)a.w;
        o[4] = (bf16)b.x; o[5] = (bf16)b.y; o[6] = (bf16)b.z; o[7] = (bf16)b.w;
        *(bf16x8*)(d + i) = o;
    }
}

// ---------------- QKV GEMM: C = A_f32 @ W_bf16^T + bias, fused cast, PIPELINED ----------------
// Double-buffered LDS. Per K-step: issue next W gload_lds + next A f32 reg-loads,
// compute current tile (MFMA hides load latency), then cvt+ds_write next A (T14).
// z=0: Q scaled by QSCALE; z=1: K; z=2: V stored transposed VT[b][h][d][s].
__global__ __launch_bounds__(256, 3)
void gemm_qkv(const float* __restrict__ A0, const float* __restrict__ A1, const float* __restrict__ A2,
              const bf16* __restrict__ W0, const bf16* __restrict__ W1, const bf16* __restrict__ W2,
              const float* __restrict__ bias0, const float* __restrict__ bias1, const float* __restrict__ bias2,
              bf16* __restrict__ O0, bf16* __restrict__ O1, bf16* __restrict__ O2) {
    constexpr int BK = 32;
    constexpr int K = D_MODEL;
    constexpr int NT = K / BK;   // 32
    __shared__ alignas(16) bf16 As[2][128 * BK];
    __shared__ alignas(16) bf16 Bs[2][128 * BK];

    int z = blockIdx.z;
    const float* A = (z == 0) ? A0 : (z == 1) ? A1 : A2;
    const bf16* W = (z == 0) ? W0 : (z == 1) ? W1 : W2;
    const float* bias = (z == 0) ? bias0 : (z == 1) ? bias1 : bias2;
    bf16* Out = (z == 0) ? O0 : (z == 1) ? O1 : O2;

    int tid = threadIdx.x;
    int lane = tid & 63, w = tid >> 6;
    int l15 = lane & 15, l4 = lane >> 4;
    int m0 = blockIdx.x * 128;
    int n0 = blockIdx.y * 128;
    int wm = w >> 1, wn = w & 1;

    f32x4 acc[4][4] = {};

    // A staging: each thread owns rows (tid>>2) and (tid>>2)+64, col chunk (tid&3)*8
    int arow = tid >> 2;
    int acol = (tid & 3) * 8;
    const float* aBase = A + (size_t)(m0 + arow) * K + acol;
    // W staging: wave w covers segs w*2, w*2+1 (16 rows each)
    int srow = lane >> 2;
    int scol = (lane & 3) * 8;

    float4 fa0, fa1, fb0, fb1;   // in-flight A registers (issue-early / write-late)

    auto loadA = [&](int kt) {
        const float* p0 = aBase + kt * BK;
        const float* p1 = p0 + (size_t)64 * K;
        fa0 = *(const float4*)p0;
        fa1 = *(const float4*)(p0 + 4);
        fb0 = *(const float4*)p1;
        fb1 = *(const float4*)(p1 + 4);
    };
    auto writeA = [&](int buf) {
        bf16x8 o;
        o[0] = (bf16)fa0.x; o[1] = (bf16)fa0.y; o[2] = (bf16)fa0.z; o[3] = (bf16)fa0.w;
        o[4] = (bf16)fa1.x; o[5] = (bf16)fa1.y; o[6] = (bf16)fa1.z; o[7] = (bf16)fa1.w;
        *(bf16x8*)(&As[buf][arow * BK + acol]) = o;
        bf16x8 p;
        p[0] = (bf16)fb0.x; p[1] = (bf16)fb0.y; p[2] = (bf16)fb0.z; p[3] = (bf16)fb0.w;
        p[4] = (bf16)fb1.x; p[5] = (bf16)fb1.y; p[6] = (bf16)fb1.z; p[7] = (bf16)fb1.w;
        *(bf16x8*)(&As[buf][(arow + 64) * BK + acol]) = p;
    };
    auto stageW = [&](int buf, int kt) {
#pragma unroll
        for (int i = 0; i < 2; ++i) {
            int seg = w * 2 + i;
            int row = seg * 16 + srow;
            const bf16* srcB = W + (size_t)(n0 + row) * K + kt * BK + scol;
            __builtin_amdgcn_global_load_lds(
                (const __attribute__((address_space(1))) void*)srcB,
                (__attribute__((address_space(3))) void*)(&Bs[buf][seg * 512]), 16, 0, 0);
        }
    };

    // prologue: tile 0
    stageW(0, 0);
    loadA(0);
    writeA(0);
    __syncthreads();

    for (int kt = 0; kt < NT; ++kt) {
        int cur = kt & 1;
        bool pre = (kt + 1 < NT);
        if (pre) {
            stageW(cur ^ 1, kt + 1);   // async DMA, drains at barrier (after compute)
            loadA(kt + 1);             // async f32 loads; consumed after compute
        }

        const bf16* pa = &As[cur][(wm * 64 + l15) * BK + l4 * 8];
        const bf16* pb = &Bs[cur][(wn * 64 + l15) * BK + l4 * 8];
        bf16x8 af[4], bv[4];
#pragma unroll
        for (int m = 0; m < 4; ++m) af[m] = *(const bf16x8*)(pa + m * 16 * BK);
#pragma unroll
        for (int n = 0; n < 4; ++n) bv[n] = *(const bf16x8*)(pb + n * 16 * BK);
#pragma unroll
        for (int m = 0; m < 4; ++m)
#pragma unroll
            for (int n = 0; n < 4; ++n)
                acc[m][n] = __builtin_amdgcn_mfma_f32_16x16x32_bf16(af[m], bv[n], acc[m][n], 0, 0, 0);

        if (pre) writeA(cur ^ 1);      // vmcnt wait lands here, after the MFMA cluster
        __syncthreads();
    }

    float bload[4];
#pragma unroll
    for (int n = 0; n < 4; ++n) bload[n] = bias[n0 + wn * 64 + n * 16 + l15];

    if (z == 2) {
        // V stored transposed: VT[(b*1024 + h*64+d)][s]
#pragma unroll
        for (int m = 0; m < 4; ++m) {
            int row = m0 + wm * 64 + m * 16 + l4 * 4;
#pragma unroll
            for (int n = 0; n < 4; ++n) {
                int col = n0 + wn * 64 + n * 16 + l15;
                float bl = bload[n];
#pragma unroll
                for (int r = 0; r < 4; ++r) {
                    float vv = acc[m][n][r] + bl;
                    int rr = row + r;
                    int bb = rr >> 10, s = rr & 1023;
                    Out[((size_t)(bb * 1024 + col)) * 1024 + s] = (bf16)vv;
                }
            }
        }
    } else {
        const float sc = (z == 0) ? QSCALE : 1.0f;
#pragma unroll
        for (int m = 0; m < 4; ++m) {
            int row = m0 + wm * 64 + m * 16 + l4 * 4;
#pragma unroll
            for (int n = 0; n < 4; ++n) {
                int col = n0 + wn * 64 + n * 16 + l15;
                float bl = bload[n];
#pragma unroll
                for (int r = 0; r < 4; ++r) {
                    float vv = (acc[m][n][r] + bl) * sc;
                    Out[(size_t)(row + r) * D_MODEL + col] = (bf16)vv;
                }
            }
        }
    }
}

// ---------------- Output projection GEMM: out = ctx_bf16 @ Wo^T + bo (f32 out) ----------------
__global__ __launch_bounds__(256, 3)
void gemm_out(const bf16* __restrict__ A, const bf16* __restrict__ W,
              const float* __restrict__ bias, float* __restrict__ Out) {
    constexpr int BK = 32;
    constexpr int K = D_MODEL;
    __shared__ alignas(16) bf16 As[128 * BK];
    __shared__ alignas(16) bf16 Bs[128 * BK];

    int tid = threadIdx.x;
    int lane = tid & 63, w = tid >> 6;
    int l15 = lane & 15, l4 = lane >> 4;
    int m0 = blockIdx.x * 128;
    int n0 = blockIdx.y * 128;
    int wm = w >> 1, wn = w & 1;

    f32x4 acc[4][4] = {};
    int srow = lane >> 2;
    int scol = (lane & 3) * 8;

    for (int k0 = 0; k0 < K; k0 += BK) {
        __syncthreads();
#pragma unroll
        for (int i = 0; i < 2; ++i) {
            int seg = w * 2 + i;
            int row = seg * 16 + srow;
            const bf16* srcA = A + (size_t)(m0 + row) * K + k0 + scol;
            const bf16* srcB = W + (size_t)(n0 + row) * K + k0 + scol;
            __builtin_amdgcn_global_load_lds(
                (const __attribute__((address_space(1))) void*)srcA,
                (__attribute__((address_space(3))) void*)(As + seg * 512), 16, 0, 0);
            __builtin_amdgcn_global_load_lds(
                (const __attribute__((address_space(1))) void*)srcB,
                (__attribute__((address_space(3))) void*)(Bs + seg * 512), 16, 0, 0);
        }
        __syncthreads();

        const bf16* pa = As + (wm * 64 + l15) * BK + l4 * 8;
        const bf16* pb = Bs + (wn * 64 + l15) * BK + l4 * 8;
        bf16x8 af[4], bv[4];
#pragma unroll
        for (int m = 0; m < 4; ++m) af[m] = *(const bf16x8*)(pa + m * 16 * BK);
#pragma unroll
        for (int n = 0; n < 4; ++n) bv[n] = *(const bf16x8*)(pb + n * 16 * BK);
#pragma unroll
        for (int m = 0; m < 4; ++m)
#pragma unroll
            for (int n = 0; n < 4; ++n)
                acc[m][n] = __builtin_amdgcn_mfma_f32_16x16x32_bf16(af[m], bv[n], acc[m][n], 0, 0, 0);
    }

    float bload[4];
#pragma unroll
    for (int n = 0; n < 4; ++n) bload[n] = bias[n0 + wn * 64 + n * 16 + l15];
#pragma unroll
    for (int m = 0; m < 4; ++m) {
        int row = m0 + wm * 64 + m * 16 + l4 * 4;
#pragma unroll
        for (int n = 0; n < 4; ++n) {
            int col = n0 + wn * 64 + n * 16 + l15;
            float bl = bload[n];
#pragma unroll
            for (int r = 0; r < 4; ++r)
                Out[(size_t)(row + r) * D_MODEL + col] = acc[m][n][r] + bl;
        }
    }
}

// ---------------- Flash attention fwd: 8 waves x 32 q = 256 q/block ----------------
// Swapped QK^T (S^T = K.Q^T), P in registers via cvt_pk + permlane32_swap, no max
// tracking (exp2-space, scores bounded). K LDS [kv][d], VT LDS [d][kv], XOR-swizzled
// via pre-swizzled global source + linear global_load_lds. Mask hoisted: per-block
// madd[1024] + per-tile all-ones flags; unmasked tiles skip all mask math.
__device__ __forceinline__ unsigned pkbf(float lo, float hi2) {
    bf16x2 t; t[0] = (bf16)lo; t[1] = (bf16)hi2;
    return __builtin_bit_cast(unsigned, t);
}

__global__ __launch_bounds__(512, 2)
void attn_fwd(const bf16* __restrict__ Qp, const bf16* __restrict__ Kp,
              const bf16* __restrict__ VT, const int* __restrict__ maskp,
              bf16* __restrict__ ctx) {
    __shared__ alignas(16) bf16 Kls[2][64 * 64];
    __shared__ alignas(16) bf16 Vls[2][64 * 64];
    __shared__ alignas(16) float madd2[SEQ];
    __shared__ int tflag[16];

    int tid = threadIdx.x;
    int lane = tid & 63, w = tid >> 6;      // 8 waves
    int l31 = lane & 31, hi = lane >> 5;

    // XCD swizzle: 256 blocks = 8 XCDs x 32; 8 whole heads per XCD.
    int fid = blockIdx.x;
    int xcd = fid & 7, idx = fid >> 3;       // idx 0..31
    int by = xcd * 8 + (idx >> 2);           // head-batch 0..63
    int bx = idx & 3;                        // q-block 0..3
    int b = by >> 4, h = by & 15;
    int q0 = bx * 256;

    // ---- mask precompute: madd2 + per-tile flags ----
    {
        int m0v = maskp[b * SEQ + tid];
        int m1v = maskp[b * SEQ + 512 + tid];
        madd2[tid] = m0v ? 0.f : MASKNEG;
        madd2[512 + tid] = m1v ? 0.f : MASKNEG;
        unsigned long long b0 = __ballot(m0v != 0);
        unsigned long long b1 = __ballot(m1v != 0);
        if (lane == 0) {
            tflag[w] = (b0 == ~0ull);
            tflag[8 + w] = (b1 == ~0ull);
        }
    }

    // Q B-fragments (col=q=lane&31, k-slot ks: d = ks*16 + hi*8 + j)
    bf16x8 qf[4];
    {
        const bf16* qb = Qp + ((size_t)(b * SEQ + q0 + w * 32 + l31)) * D_MODEL + h * 64 + hi * 8;
#pragma unroll
        for (int ks = 0; ks < 4; ++ks) qf[ks] = *(const bf16x8*)(qb + ks * 16);
    }

    f32x16 oacc0 = {}, oacc1 = {};
    float lsum = 0.f;

    auto stage = [&](int buf, int kt) {
        int kv0 = kt * 64;
        int row = w * 8 + (lane >> 3);          // wave w stages rows [8w, 8w+8)
        int cs = ((lane & 7) ^ (row & 7)) * 8;  // pre-swizzled source chunk
        const bf16* srcK = Kp + ((size_t)(b * SEQ + kv0 + row)) * D_MODEL + h * 64 + cs;
        __builtin_amdgcn_global_load_lds(
            (const __attribute__((address_space(1))) void*)srcK,
            (__attribute__((address_space(3))) void*)(&Kls[buf][w * 512]), 16, 0, 0);
        const bf16* srcV = VT + ((size_t)(b * 1024 + h * 64 + row)) * SEQ + kv0 + cs;
        __builtin_amdgcn_global_load_lds(
            (const __attribute__((address_space(1))) void*)srcV,
            (__attribute__((address_space(3))) void*)(&Vls[buf][w * 512]), 16, 0, 0);
    };

    stage(0, 0);
    __syncthreads();

    for (int kt = 0; kt < SEQ / 64; ++kt) {
        int cur = kt & 1;
        if (kt + 1 < SEQ / 64) stage(cur ^ 1, kt + 1);

        // ---- QK^T (swapped): S^T[kv][q] ----
        f32x16 p0 = {}, p1 = {};
        __builtin_amdgcn_s_setprio(1);
#pragma unroll
        for (int ks = 0; ks < 4; ++ks) {
            int slot = ((2 * ks + hi) ^ (l31 & 7)) * 8;
            bf16x8 k0 = *(const bf16x8*)(&Kls[cur][l31 * 64 + slot]);
            bf16x8 k1 = *(const bf16x8*)(&Kls[cur][(32 + l31) * 64 + slot]);
            p0 = __builtin_amdgcn_mfma_f32_32x32x16_bf16(k0, qf[ks], p0, 0, 0, 0);
            p1 = __builtin_amdgcn_mfma_f32_32x32x16_bf16(k1, qf[ks], p1, 0, 0, 0);
        }
        __builtin_amdgcn_s_setprio(0);

        // ---- exp2 + row-sum (reg r -> kv = (r&3) + 8*(r>>2) + 4*hi) ----
        float a0 = 0.f, a1 = 0.f, a2 = 0.f, a3 = 0.f;
        if (tflag[kt]) {
#pragma unroll
            for (int g = 0; g < 4; ++g) {
                float s0 = 0.f, s1 = 0.f;
#pragma unroll
                for (int c = 0; c < 4; ++c) {
                    int r = g * 4 + c;
                    float e0 = exp2f(p0[r]);
                    float e1 = exp2f(p1[r]);
                    p0[r] = e0; p1[r] = e1;
                    s0 += e0; s1 += e1;
                }
                if (g == 0) a0 = s0 + s1;
                else if (g == 1) a1 = s0 + s1;
                else if (g == 2) a2 = s0 + s1;
                else a3 = s0 + s1;
            }
        } else {
            const float* mb = &madd2[kt * 64];
#pragma unroll
            for (int g = 0; g < 4; ++g) {
                f32x4 mk0 = *(const f32x4*)(mb + g * 8 + hi * 4);
                f32x4 mk1 = *(const f32x4*)(mb + 32 + g * 8 + hi * 4);
                float s0 = 0.f, s1 = 0.f;
#pragma unroll
                for (int c = 0; c < 4; ++c) {
                    int r = g * 4 + c;
                    float e0 = exp2f(p0[r] + mk0[c]);
                    float e1 = exp2f(p1[r] + mk1[c]);
                    p0[r] = e0; p1[r] = e1;
                    s0 += e0; s1 += e1;
                }
                if (g == 0) a0 = s0 + s1;
                else if (g == 1) a1 = s0 + s1;
                else if (g == 2) a2 = s0 + s1;
                else a3 = s0 + s1;
            }
        }
        float acc_s = (a0 + a1) + (a2 + a3);
        acc_s += __shfl_xor(acc_s, 32);
        lsum += acc_s;

        // ---- pack P -> PV A-fragments (cvt_pk + permlane32_swap) ----
        union FragU { bf16x8 v; unsigned u[4]; };
        FragU pa0, pa1, pa2, pa3;
#define PKSW(PV, RA, RB, DST)  { \
            unsigned a_ = pkbf(PV[RA], PV[(RA) + 1]); \
            unsigned b_ = pkbf(PV[RB], PV[(RB) + 1]); \
            auto rr_ = __builtin_amdgcn_permlane32_swap(a_, b_, false, false); \
            DST.u[((RA) & 3) >> 1] = rr_[0]; DST.u[(((RA) & 3) >> 1) + 2] = rr_[1]; }
        PKSW(p0, 0, 4,  pa0);
        PKSW(p0, 2, 6,  pa0);
        PKSW(p0, 8, 12, pa1);
        PKSW(p0, 10, 14, pa1);
        PKSW(p1, 0, 4,  pa2);
        PKSW(p1, 2, 6,  pa2);
        PKSW(p1, 8, 12, pa3);
        PKSW(p1, 10, 14, pa3);
#undef PKSW

        // ---- PV: O += P[q][kv] . V[kv][d] ----
        __builtin_amdgcn_s_setprio(1);
#pragma unroll
        for (int ks = 0; ks < 4; ++ks) {
            bf16x8 pav = (ks == 0) ? pa0.v : (ks == 1) ? pa1.v : (ks == 2) ? pa2.v : pa3.v;
            int slot = ((2 * ks + hi) ^ (l31 & 7)) * 8;
            bf16x8 v0 = *(const bf16x8*)(&Vls[cur][l31 * 64 + slot]);
            bf16x8 v1 = *(const bf16x8*)(&Vls[cur][(32 + l31) * 64 + slot]);
            oacc0 = __builtin_amdgcn_mfma_f32_32x32x16_bf16(pav, v0, oacc0, 0, 0, 0);
            oacc1 = __builtin_amdgcn_mfma_f32_32x32x16_bf16(pav, v1, oacc1, 0, 0, 0);
        }
        __builtin_amdgcn_s_setprio(0);

        __syncthreads();
    }

    // ---- epilogue: normalize and store ----
#pragma unroll
    for (int g = 0; g < 4; ++g) {
#pragma unroll
        for (int c = 0; c < 4; ++c) {
            int r = g * 4 + c;
            int qloc = c + g * 8 + hi * 4;
            float sden = __shfl(lsum, qloc);
            float inv = 1.0f / sden;
            int qg = q0 + w * 32 + qloc;
            size_t base = ((size_t)(b * SEQ + qg)) * D_MODEL + h * 64;
            ctx[base + l31]      = (bf16)(oacc0[r] * inv);
            ctx[base + 32 + l31] = (bf16)(oacc1[r] * inv);
        }
    }
}

// ---------------- launch ----------------
extern "C" void kernel_launch(void* const* d_in, const int* in_sizes, int n_in,
                              void* d_out, int out_size, void* d_ws, size_t ws_size,
                              hipStream_t stream) {
    const float* q  = (const float*)d_in[0];
    const float* k  = (const float*)d_in[1];
    const float* v  = (const float*)d_in[2];
    const int* mask = (const int*)d_in[3];
    const float* Wq = (const float*)d_in[4];
    const float* bq = (const float*)d_in[5];
    const float* Wk = (const float*)d_in[6];
    const float* bk = (const float*)d_in[7];
    const float* Wv = (const float*)d_in[8];
    const float* bv = (const float*)d_in[9];
    const float* Wo = (const float*)d_in[10];
    const float* bo = (const float*)d_in[11];
    float* out = (float*)d_out;

    char* ws = (char*)d_ws;
    size_t szQKV = (size_t)MTOT * D_MODEL * sizeof(bf16);   // 8 MB
    size_t szW = (size_t)D_MODEL * D_MODEL * sizeof(bf16);  // 2 MB
    bf16* Wqb = (bf16*)ws; ws += szW;
    bf16* Wkb = (bf16*)ws; ws += szW;
    bf16* Wvb = (bf16*)ws; ws += szW;
    bf16* Wob = (bf16*)ws; ws += szW;
    bf16* Qp  = (bf16*)ws; ws += szQKV;
    bf16* Kp  = (bf16*)ws; ws += szQKV;
    bf16* VT  = (bf16*)ws; ws += szQKV;   // transposed V: [B][H][64][SEQ]
    bf16* ctx = (bf16*)ws; ws += szQKV;

    dim3 gc(256, 4, 1);
    cast_w<<<gc, 256, 0, stream>>>(Wq, Wk, Wv, Wo, Wqb, Wkb, Wvb, Wob);

    dim3 g1(MTOT / 128, D_MODEL / 128, 3);
    gemm_qkv<<<g1, 256, 0, stream>>>(q, k, v, Wqb, Wkb, Wvb,
                                     bq, bk, bv, Qp, Kp, VT);

    attn_fwd<<<dim3(256), 512, 0, stream>>>(Qp, Kp, VT, mask, ctx);

    dim3 g3(MTOT / 128, D_MODEL / 128, 1);
    gemm_out<<<g3, 256, 0, stream>>>(ctx, Wob, bo, out);
}